// Round 1
// baseline (33937.027 us; speedup 1.0000x reference)
//
#include <hip/hip_runtime.h>

// Problem: N=512 batch, T=256, H=512, D=9. 257 encode steps + 256 decode steps.
// Gate order (PyTorch LSTMCell): i, f, g, o -> W rows [0:512),[512:1024),[1024:1536),[1536:2048)

#define TT     256
#define HH     512
#define DD     9
#define TP1    257
#define NSTEP  513      // 257 encode + 256 decode
#define THREADS 512

// grid decomposition: 4 groups x 64 wgs; group owns 128 batch, wg owns 8 hidden units (32 gate rows)
#define WPG    64
#define UPW    8
#define ROWS   32
#define BSL    128

// ws layout (float offsets)
#define WPACK_OFF 0
#define WPACK_SZ  (2048 * 512)          // 4 MB: W_pack[wl][k][32]
#define HT0_OFF   (WPACK_SZ)            // h_T buffer 0: [512 k][512 n]
#define HT1_OFF   (HT0_OFF + 512 * 512)
#define CWS_OFF   (HT1_OFF + 512 * 512) // c state: [512 j][512 n]

__device__ __forceinline__ float sigmoidf_(float v) {
    return 1.0f / (1.0f + __expf(-v));
}
__device__ __forceinline__ float tanhf_(float v) {
    // 1 - 2/(e^{2v}+1); saturates correctly via inf/0
    return 1.0f - 2.0f / (__expf(2.0f * v) + 1.0f);
}

// One-time packing: W_pack[wl][k][r] = W_hh[gate*512 + wl*8 + unit][k], r = gate*8+unit.
// Also h_T[0][j][n] = h0[j], c[j][n] = c0[j].
__global__ void rnn_init_kernel(const float* __restrict__ W_hh,
                                const float* __restrict__ h0,
                                const float* __restrict__ c0,
                                float* __restrict__ ws) {
    int idx = blockIdx.x * blockDim.x + threadIdx.x;   // 0 .. 2048*512-1
    {
        int r    = idx & 31;
        int k    = (idx >> 5) & 511;
        int wl   = idx >> 14;            // / (32*512)
        int gate = r >> 3, unit = r & 7;
        int grow = gate * 512 + wl * 8 + unit;
        ws[WPACK_OFF + idx] = W_hh[grow * 512 + k];
    }
    if (idx < 512 * 512) {
        int j = idx >> 9;
        ws[HT0_OFF + idx] = h0[j];
        ws[CWS_OFF + idx] = c0[j];
    }
}

// Per-step kernel. s in [0,513]; s==513 is the tail (fc for td=255 only).
// Reads h_T[s&1], writes h_T[(s+1)&1].
// If s>=258: also emits fc output for td = s-258 from h_T[s&1] (h after step s-1).
__global__ __launch_bounds__(THREADS)
void rnn_step_kernel(const float* __restrict__ x,
                     const float* __restrict__ W_ih,
                     const float* __restrict__ b_ih,
                     const float* __restrict__ b_hh,
                     const float* __restrict__ fc_W,
                     const float* __restrict__ fc_b,
                     float* __restrict__ ws,
                     float* __restrict__ out,
                     int s) {
    const int wg  = blockIdx.x;
    const int g   = wg >> 6;          // group 0..3
    const int wl  = wg & 63;          // wg within group
    const int j0  = wl * UPW;         // hidden-unit base
    const int nb0 = g * BSL;          // batch base
    const int tid = threadIdx.x;

    const float* __restrict__ Wp   = ws + WPACK_OFF + wl * (512 * ROWS);
    const float* __restrict__ hcur = ws + (((s & 1) == 0) ? HT0_OFF : HT1_OFF);
    float*       __restrict__ hnxt = ws + (((s & 1) == 0) ? HT1_OFF : HT0_OFF);
    float*       __restrict__ cws  = ws + CWS_OFF;

    __shared__ float gates[ROWS][BSL];   // 16 KB
    __shared__ float hnew[UPW][BSL];     // 4 KB
    __shared__ float fcw[DD][HH];        // 18 KB
    __shared__ float fcb[DD];
    __shared__ float wih[ROWS][12];      // 1.5 KB
    __shared__ float bias[ROWS];

    const bool enc     = (s <= 256);
    const bool dec_out = (s >= 258);

    // ---- stage small constants ----
    if (tid < ROWS) {
        int gate = tid >> 3, unit = tid & 7;
        int grow = gate * 512 + j0 + unit;
        bias[tid] = b_ih[grow] + b_hh[grow];
    }
    if (enc) {
        for (int i = tid; i < ROWS * DD; i += THREADS) {
            int r = i / DD, d = i % DD;
            int gate = r >> 3, unit = r & 7;
            wih[r][d] = W_ih[(gate * 512 + j0 + unit) * DD + d];
        }
    }
    if (dec_out) {
        for (int i = tid; i < DD * HH; i += THREADS) fcw[i / HH][i % HH] = fc_W[i];
        if (tid < DD) fcb[tid] = fc_b[tid];
    }
    __syncthreads();

    // ---- fc output for previous step's h (decode phase) ----
    if (dec_out) {
        int w = tid >> 3, l8 = tid & 7;
        if (w < 2 * DD) {
            int bsel = w / DD, d = w % DD;
            int n = nb0 + wl * 2 + bsel;
            float acc = 0.f;
            for (int k = l8; k < HH; k += 8)
                acc += hcur[k * 512 + n] * fcw[d][k];
            acc += __shfl_down(acc, 4, 8);
            acc += __shfl_down(acc, 2, 8);
            acc += __shfl_down(acc, 1, 8);
            if (l8 == 0) {
                int td = s - 258;
                out[n * (TT * DD) + td * DD + d] =
                    1.0f / (1.0f + __expf(-(acc + fcb[d])));
            }
        }
    }
    if (s >= NSTEP) return;   // tail launch: fc only (uniform branch)

    // ---- GEMM: gates[r][b] = sum_k h[n][k] * W_hh[row][k] ----
    // thread (tb, tr2): tb = tid>>4 covers batch tb*4..+3; tr2 = tid&15 covers rows tr2*2..+1
    const int tb = tid >> 4, tr2 = tid & 15;
    const float* hp = hcur + nb0 + tb * 4;
    const float* wp = Wp + tr2 * 2;
    float a00 = 0.f, a01 = 0.f, a10 = 0.f, a11 = 0.f;
    float a20 = 0.f, a21 = 0.f, a30 = 0.f, a31 = 0.f;
#pragma unroll 8
    for (int k = 0; k < HH; ++k) {
        float4 hv = *(const float4*)(hp + (size_t)k * 512);
        float2 wv = *(const float2*)(wp + (size_t)k * ROWS);
        a00 += hv.x * wv.x; a01 += hv.x * wv.y;
        a10 += hv.y * wv.x; a11 += hv.y * wv.y;
        a20 += hv.z * wv.x; a21 += hv.z * wv.y;
        a30 += hv.w * wv.x; a31 += hv.w * wv.y;
    }
    {
        int r0 = tr2 * 2;
        *(float4*)&gates[r0][tb * 4]     = make_float4(a00, a10, a20, a30);
        *(float4*)&gates[r0 + 1][tb * 4] = make_float4(a01, a11, a21, a31);
    }
    __syncthreads();

    // ---- LSTM cell: thread owns unit jc = tid&7, batches (tid>>3)*2 + {0,1} ----
    {
        int jc = tid & 7;
        int b0c = (tid >> 3) * 2;
        int j = j0 + jc;
#pragma unroll
        for (int i = 0; i < 2; ++i) {
            int b = b0c + i, n = nb0 + b;
            float vi = gates[jc][b]      + bias[jc];
            float vf = gates[8 + jc][b]  + bias[8 + jc];
            float vg = gates[16 + jc][b] + bias[16 + jc];
            float vo = gates[24 + jc][b] + bias[24 + jc];
            if (enc) {
                const float* xp = x + (size_t)n * (TP1 * DD) + (size_t)s * DD;
                float xv[DD];
#pragma unroll
                for (int d = 0; d < DD; ++d) xv[d] = xp[d];
                float di = 0.f, df = 0.f, dg = 0.f, dq = 0.f;
#pragma unroll
                for (int d = 0; d < DD; ++d) {
                    di += xv[d] * wih[jc][d];
                    df += xv[d] * wih[8 + jc][d];
                    dg += xv[d] * wih[16 + jc][d];
                    dq += xv[d] * wih[24 + jc][d];
                }
                vi += di; vf += df; vg += dg; vo += dq;
            }
            float c_old = cws[(size_t)j * 512 + n];
            float si = sigmoidf_(vi), sf = sigmoidf_(vf), so = sigmoidf_(vo);
            float tg = tanhf_(vg);
            float cn = sf * c_old + si * tg;
            cws[(size_t)j * 512 + n] = cn;
            hnew[jc][b] = so * tanhf_(cn);
        }
    }
    __syncthreads();

    // ---- write h_new to h_T[nxt]: rows j0..j0+7, cols nb0..nb0+127 ----
    {
        int u = tid >> 6, seg = tid & 63;   // u 0..7, seg 0..63
        float2 v = *(const float2*)&hnew[u][seg * 2];
        *(float2*)&hnxt[(size_t)(j0 + u) * 512 + nb0 + seg * 2] = v;
    }
}

extern "C" void kernel_launch(void* const* d_in, const int* in_sizes, int n_in,
                              void* d_out, int out_size, void* d_ws, size_t ws_size,
                              hipStream_t stream) {
    (void)in_sizes; (void)n_in; (void)out_size; (void)ws_size;
    const float* x    = (const float*)d_in[0];
    const float* W_ih = (const float*)d_in[1];
    const float* W_hh = (const float*)d_in[2];
    const float* b_ih = (const float*)d_in[3];
    const float* b_hh = (const float*)d_in[4];
    const float* fc_W = (const float*)d_in[5];
    const float* fc_b = (const float*)d_in[6];
    const float* h0   = (const float*)d_in[7];
    const float* c0   = (const float*)d_in[8];
    float* out = (float*)d_out;
    float* ws  = (float*)d_ws;

    // pack weights + init state (re-done every call: deterministic, graph-safe)
    hipLaunchKernelGGL(rnn_init_kernel, dim3(4096), dim3(256), 0, stream,
                       W_hh, h0, c0, ws);

    // 513 LSTM steps + 1 tail fc launch
    for (int s = 0; s <= NSTEP; ++s) {
        hipLaunchKernelGGL(rnn_step_kernel, dim3(256), dim3(THREADS), 0, stream,
                           x, W_ih, b_ih, b_hh, fc_W, fc_b, ws, out, s);
    }
}

// Round 2
// 15104.803 us; speedup vs baseline: 2.2468x; 2.2468x over previous
//
#include <hip/hip_runtime.h>

// Problem: N=512 batch, T=256, H=512, D=9. 257 encode steps + 256 decode steps.
// Gate order (PyTorch LSTMCell): i, f, g, o -> W rows [0:512),[512:1024),[1024:1536),[1536:2048)

#define TT     256
#define HH     512
#define DD     9
#define TP1    257
#define NSTEP  513      // 257 encode + 256 decode
#define THREADS 512

// grid decomposition: 4 groups x 64 wgs; group owns 128 batch, wg owns 8 hidden units (32 gate rows)
#define UPW    8
#define ROWS   32
#define BSL    128
#define KC     32       // K-chunk staged in LDS
#define NC     16       // 512 / KC

// ws layout (float offsets)
#define WPACK_OFF 0
#define WPACK_SZ  (2048 * 512)          // 4 MB: W_pack[wl][k][32]
#define HT0_OFF   (WPACK_SZ)            // h_T buffer 0: [512 k][512 n]
#define HT1_OFF   (HT0_OFF + 512 * 512)
#define CWS_OFF   (HT1_OFF + 512 * 512) // c state: [512 j][512 n]

__device__ __forceinline__ float sigmoidf_(float v) {
    return 1.0f / (1.0f + __expf(-v));
}
__device__ __forceinline__ float tanhf_(float v) {
    return 1.0f - 2.0f / (__expf(2.0f * v) + 1.0f);
}

// One-time packing: W_pack[wl][k][r] = W_hh[gate*512 + wl*8 + unit][k], r = gate*8+unit.
__global__ void rnn_init_kernel(const float* __restrict__ W_hh,
                                const float* __restrict__ h0,
                                const float* __restrict__ c0,
                                float* __restrict__ ws) {
    int idx = blockIdx.x * blockDim.x + threadIdx.x;   // 0 .. 2048*512-1
    {
        int r    = idx & 31;
        int k    = (idx >> 5) & 511;
        int wl   = idx >> 14;            // / (32*512)
        int gate = r >> 3, unit = r & 7;
        int grow = gate * 512 + wl * 8 + unit;
        ws[WPACK_OFF + idx] = W_hh[grow * 512 + k];
    }
    if (idx < 512 * 512) {
        int j = idx >> 9;
        ws[HT0_OFF + idx] = h0[j];
        ws[CWS_OFF + idx] = c0[j];
    }
}

// issue global loads for chunk with base row k0 into regs (h: 2 x float4, w: 1 x float4 for tid<256)
#define LOADC(k0, A, B, Cw) do {                                                          \
    A = *(const float4*)(hcur + (size_t)((k0) + (tid >> 5)) * 512 + nb0 + (tid & 31) * 4);\
    B = *(const float4*)(hcur + (size_t)((k0) + 16 + (tid >> 5)) * 512 + nb0 + (tid & 31) * 4);\
    if (tid < 256)                                                                        \
        Cw = *(const float4*)(Wp + (size_t)((k0) + (tid >> 3)) * 32 + (tid & 7) * 4);     \
} while (0)

#define STOREC(b, A, B, Cw) do {                                                          \
    *(float4*)&hbuf[b][tid >> 5][(tid & 31) * 4]      = A;                                \
    *(float4*)&hbuf[b][16 + (tid >> 5)][(tid & 31) * 4] = B;                              \
    if (tid < 256) *(float4*)&wbuf[b][tid >> 3][(tid & 7) * 4] = Cw;                      \
} while (0)

// Per-step kernel. s in [0,513]; s==513 is tail (fc for td=255 only).
// Reads h_T[s&1], writes h_T[(s+1)&1]. If s>=258: fc output for td = s-258 from h_T[s&1].
__global__ __launch_bounds__(THREADS)
void rnn_step_kernel(const float* __restrict__ x,
                     const float* __restrict__ W_ih,
                     const float* __restrict__ b_ih,
                     const float* __restrict__ b_hh,
                     const float* __restrict__ fc_W,
                     const float* __restrict__ fc_b,
                     float* __restrict__ ws,
                     float* __restrict__ out,
                     int s) {
    const int wg  = blockIdx.x;
    const int g   = wg >> 6;          // group 0..3 (batch slice)
    const int wl  = wg & 63;          // wg within group (hidden-unit slice)
    const int j0  = wl * UPW;
    const int nb0 = g * BSL;
    const int tid = threadIdx.x;

    const float* __restrict__ Wp   = ws + WPACK_OFF + wl * (512 * ROWS);
    const float* __restrict__ hcur = ws + (((s & 1) == 0) ? HT0_OFF : HT1_OFF);
    float*       __restrict__ hnxt = ws + (((s & 1) == 0) ? HT1_OFF : HT0_OFF);
    float*       __restrict__ cws  = ws + CWS_OFF;

    __shared__ float hbuf[2][KC][BSL];   // 32 KB (double-buffered h chunk)
    __shared__ float wbuf[2][KC][ROWS];  // 8 KB  (double-buffered W chunk)
    __shared__ float gates[ROWS][BSL];   // 16 KB
    __shared__ float hnew[UPW][BSL];     // 4 KB
    __shared__ float wih[ROWS][12];      // 1.5 KB
    __shared__ float bias[ROWS];

    const bool enc     = (s <= 256);
    const bool dec_out = (s >= 258);

    // ---- issue chunk-0 prefetch FIRST (latency overlaps fc / constant staging) ----
    float4 rh0, rh1, rw;
    LOADC(0, rh0, rh1, rw);

    // ---- stage small constants ----
    if (tid < ROWS) {
        int gate = tid >> 3, unit = tid & 7;
        int grow = gate * 512 + j0 + unit;
        bias[tid] = b_ih[grow] + b_hh[grow];
    }
    if (enc) {
        for (int i = tid; i < ROWS * DD; i += THREADS) {
            int r = i / DD, d = i % DD;
            int gate = r >> 3, unit = r & 7;
            wih[r][d] = W_ih[(gate * 512 + j0 + unit) * DD + d];
        }
    }

    // ---- fc output for previous step's h (decode phase); fc_W straight from L2 ----
    if (dec_out) {
        int w = tid >> 4, l16 = tid & 15;
        if (w < 2 * DD) {
            int bsel = w / DD, d = w % DD;
            int n = nb0 + wl * 2 + bsel;
            float acc = 0.f;
#pragma unroll 8
            for (int k = l16; k < HH; k += 16)
                acc += hcur[(size_t)k * 512 + n] * fc_W[d * HH + k];
            acc += __shfl_down(acc, 8, 16);
            acc += __shfl_down(acc, 4, 16);
            acc += __shfl_down(acc, 2, 16);
            acc += __shfl_down(acc, 1, 16);
            if (l16 == 0) {
                int td = s - 258;
                out[(size_t)n * (TT * DD) + td * DD + d] =
                    1.0f / (1.0f + __expf(-(acc + fc_b[d])));
            }
        }
    }
    if (s >= NSTEP) return;   // tail launch: fc only (uniform branch)

    // ---- pipelined GEMM: gates[r][b] = sum_k h[n][k] * W_hh[row][k] ----
    // thread (tb, tr2): tb = tid>>4 covers batch tb*4..+3; tr2 = tid&15 covers rows tr2*2..+1
    const int tb = tid >> 4, tr2 = tid & 15;
    float a00 = 0.f, a01 = 0.f, a10 = 0.f, a11 = 0.f;
    float a20 = 0.f, a21 = 0.f, a30 = 0.f, a31 = 0.f;

    for (int c = 0; c < NC; ++c) {
        float4 nh0, nh1, nw;
        if (c + 1 < NC) LOADC((c + 1) * KC, nh0, nh1, nw);   // prefetch next chunk (stays in flight)
        STOREC(c & 1, rh0, rh1, rw);                          // waits only on rh*/rw vmcnt
        // raw barrier: LDS-only drain; next-chunk global loads stay in flight
        asm volatile("s_waitcnt lgkmcnt(0)" ::: "memory");
        __builtin_amdgcn_s_barrier();

        const float* hb = &hbuf[c & 1][0][tb * 4];
        const float* wb = &wbuf[c & 1][0][tr2 * 2];
#pragma unroll
        for (int k = 0; k < KC; ++k) {
            float4 hv = *(const float4*)(hb + k * BSL);
            float2 wv = *(const float2*)(wb + k * ROWS);
            a00 += hv.x * wv.x; a01 += hv.x * wv.y;
            a10 += hv.y * wv.x; a11 += hv.y * wv.y;
            a20 += hv.z * wv.x; a21 += hv.z * wv.y;
            a30 += hv.w * wv.x; a31 += hv.w * wv.y;
        }
        if (c + 1 < NC) { rh0 = nh0; rh1 = nh1; rw = nw; }
    }

    {
        int r0 = tr2 * 2;
        *(float4*)&gates[r0][tb * 4]     = make_float4(a00, a10, a20, a30);
        *(float4*)&gates[r0 + 1][tb * 4] = make_float4(a01, a11, a21, a31);
    }
    __syncthreads();

    // ---- LSTM cell: thread owns unit jc = tid&7, batches (tid>>3)*2 + {0,1} ----
    {
        int jc = tid & 7;
        int b0c = (tid >> 3) * 2;
        int j = j0 + jc;
#pragma unroll
        for (int i = 0; i < 2; ++i) {
            int b = b0c + i, n = nb0 + b;
            float vi = gates[jc][b]      + bias[jc];
            float vf = gates[8 + jc][b]  + bias[8 + jc];
            float vg = gates[16 + jc][b] + bias[16 + jc];
            float vo = gates[24 + jc][b] + bias[24 + jc];
            if (enc) {
                const float* xp = x + (size_t)n * (TP1 * DD) + (size_t)s * DD;
                float xv[DD];
#pragma unroll
                for (int d = 0; d < DD; ++d) xv[d] = xp[d];
                float di = 0.f, df = 0.f, dg = 0.f, dq = 0.f;
#pragma unroll
                for (int d = 0; d < DD; ++d) {
                    di += xv[d] * wih[jc][d];
                    df += xv[d] * wih[8 + jc][d];
                    dg += xv[d] * wih[16 + jc][d];
                    dq += xv[d] * wih[24 + jc][d];
                }
                vi += di; vf += df; vg += dg; vo += dq;
            }
            float c_old = cws[(size_t)j * 512 + n];
            float si = sigmoidf_(vi), sf = sigmoidf_(vf), so = sigmoidf_(vo);
            float tg = tanhf_(vg);
            float cn = sf * c_old + si * tg;
            cws[(size_t)j * 512 + n] = cn;
            hnew[jc][b] = so * tanhf_(cn);
        }
    }
    __syncthreads();

    // ---- write h_new to h_T[nxt]: rows j0..j0+7, cols nb0..nb0+127 ----
    {
        int u = tid >> 6, seg = tid & 63;   // u 0..7, seg 0..63
        float2 v = *(const float2*)&hnew[u][seg * 2];
        *(float2*)&hnxt[(size_t)(j0 + u) * 512 + nb0 + seg * 2] = v;
    }
}

extern "C" void kernel_launch(void* const* d_in, const int* in_sizes, int n_in,
                              void* d_out, int out_size, void* d_ws, size_t ws_size,
                              hipStream_t stream) {
    (void)in_sizes; (void)n_in; (void)out_size; (void)ws_size;
    const float* x    = (const float*)d_in[0];
    const float* W_ih = (const float*)d_in[1];
    const float* W_hh = (const float*)d_in[2];
    const float* b_ih = (const float*)d_in[3];
    const float* b_hh = (const float*)d_in[4];
    const float* fc_W = (const float*)d_in[5];
    const float* fc_b = (const float*)d_in[6];
    const float* h0   = (const float*)d_in[7];
    const float* c0   = (const float*)d_in[8];
    float* out = (float*)d_out;
    float* ws  = (float*)d_ws;

    hipLaunchKernelGGL(rnn_init_kernel, dim3(4096), dim3(256), 0, stream,
                       W_hh, h0, c0, ws);

    for (int s = 0; s <= NSTEP; ++s) {
        hipLaunchKernelGGL(rnn_step_kernel, dim3(256), dim3(THREADS), 0, stream,
                           x, W_ih, b_ih, b_hh, fc_W, fc_b, ws, out, s);
    }
}